// Round 7
// baseline (1205.001 us; speedup 1.0000x reference)
//
#include <hip/hip_runtime.h>

#define H  64
#define TT 512
#define BB 512

typedef _Float16 half8 __attribute__((ext_vector_type(8)));
typedef float    f32x4 __attribute__((ext_vector_type(4)));

__device__ __forceinline__ float frcp(float x) { return __builtin_amdgcn_rcpf(x); }
__device__ __forceinline__ float sigm(float x) { return frcp(1.f + __expf(-x)); }
__device__ __forceinline__ float tanh_fast(float x) { return 1.f - 2.f * frcp(__expf(2.f * x) + 1.f); }

// ---------------------------------------------------------------------------
// xpad: [B*T][32] fp16, cols 0..3 = x (fp32->fp16), cols 4..31 = 0.
// ---------------------------------------------------------------------------
__global__ __launch_bounds__(256) void xpad_prep(const float* __restrict__ x,
                                                 _Float16* __restrict__ xpad) {
    int gid = blockIdx.x * 256 + threadIdx.x;
    int row = gid >> 2, q = gid & 3;
    half8 v = {0,0,0,0,0,0,0,0};
    if (q == 0) {
        float4 xv = ((const float4*)x)[row];
        v[0] = (_Float16)xv.x; v[1] = (_Float16)xv.y;
        v[2] = (_Float16)xv.z; v[3] = (_Float16)xv.w;
    }
    *(half8*)(xpad + (size_t)row * 32 + q * 8) = v;
}

// ---------------------------------------------------------------------------
// MFMA LSTM layer 0. Block = 512 thr = 8 waves = TWO independent chain-groups
// (16 chains each, own LDS h-buffer). 2 waves/SIMD so one group's latency
// stalls are filled by the other group's issue. 1 barrier/step (shared).
// ---------------------------------------------------------------------------
__global__ __launch_bounds__(512) void lstm_l0(
    const _Float16* __restrict__ xpad,
    const float* __restrict__ WihF, const float* __restrict__ WhhF, const float* __restrict__ bF,
    const float* __restrict__ WihB, const float* __restrict__ WhhB, const float* __restrict__ bB,
    _Float16* __restrict__ out0)
{
    const int tid  = threadIdx.x;
    const int grp  = tid >> 8;            // 0/1: which chain-group in this block
    const int tid8 = tid & 255;
    const int w = tid8 >> 6, l = tid8 & 63, m = l & 15, q = l >> 4;

    const int gg  = blockIdx.x * 2 + grp; // global group 0..63
    const int dir = gg & 1;
    const int b0  = (gg >> 1) * 16;

    const float* Wih = dir ? WihB : WihF;
    const float* Whh = dir ? WhhB : WhhF;
    const float* bia = dir ? bB   : bF;

    half8 Bh[4][2], Bx[4];
    float bv[4];
#pragma unroll
    for (int g = 0; g < 4; ++g) {
        const int n = g * 64 + w * 16 + m;
        bv[g] = bia[n];
#pragma unroll
        for (int s = 0; s < 2; ++s) {
            const float* src = Whh + n * 64 + s * 32 + q * 8;
            half8 tmp;
#pragma unroll
            for (int j = 0; j < 8; ++j) tmp[j] = (_Float16)src[j];
            Bh[g][s] = tmp;
        }
        half8 tx;
#pragma unroll
        for (int j = 0; j < 8; ++j) {
            int k = q * 8 + j;
            tx[j] = (k < 4) ? (_Float16)Wih[n * 4 + k] : (_Float16)0.f;
        }
        Bx[g] = tx;
    }

    __shared__ _Float16 hbuf[2][2][1024];           // [group][pingpong][16ch x 64u]
    ((unsigned long long*)hbuf[grp][0])[tid8] = 0ULL;
    __syncthreads();

    float c[4] = {0.f, 0.f, 0.f, 0.f};
    const int dt = dir ? -1 : 1;
    int t = dir ? TT - 1 : 0;
    const _Float16* xrow = xpad + (size_t)(b0 + m) * TT * 32 + q * 8;
    const int swz = (m & 7) * 16;

    half8 ax  = *(const half8*)(xrow + t * 32);
    int t1 = t + dt; if (t1 < 0 || t1 >= TT) t1 = t;
    half8 axn = *(const half8*)(xrow + t1 * 32);
    int p = 0;

    for (int s = 0; s < TT; ++s) {
        int t2 = t + 2 * dt; if (t2 < 0 || t2 >= TT) t2 = t;
        half8 axn2 = *(const half8*)(xrow + t2 * 32);

        const char* hb = (const char*)hbuf[grp][p];
        half8 ah0 = *(const half8*)(hb + m * 128 + ((     q * 16 + swz) & 127));
        half8 ah1 = *(const half8*)(hb + m * 128 + ((64 + q * 16 + swz) & 127));

        f32x4 acc[4];
#pragma unroll
        for (int g = 0; g < 4; ++g) {
            f32x4 a = {bv[g], bv[g], bv[g], bv[g]};
            a = __builtin_amdgcn_mfma_f32_16x16x32_f16(ax,  Bx[g],    a, 0, 0, 0);
            a = __builtin_amdgcn_mfma_f32_16x16x32_f16(ah0, Bh[g][0], a, 0, 0, 0);
            acc[g] = __builtin_amdgcn_mfma_f32_16x16x32_f16(ah1, Bh[g][1], a, 0, 0, 0);
        }

        char* hbn = (char*)hbuf[grp][p ^ 1];
#pragma unroll
        for (int i = 0; i < 4; ++i) {
            float e_i = sigm(acc[0][i]), e_f = sigm(acc[1][i]);
            float e_g = tanh_fast(acc[2][i]), e_o = sigm(acc[3][i]);
            c[i] = e_f * c[i] + e_i * e_g;
            float hh = e_o * tanh_fast(c[i]);
            const int ch = q * 4 + i;
            out0[((size_t)(b0 + ch) * TT + t) * 128 + dir * 64 + w * 16 + m] = (_Float16)hh;
            *(_Float16*)(hbn + ch * 128 + (((w * 16 + m) * 2 + (ch & 7) * 16) & 127)) = (_Float16)hh;
        }
        __syncthreads();
        p ^= 1; t += dt; ax = axn; axn = axn2;
    }
}

// ---------------------------------------------------------------------------
// MFMA LSTM layer 1: K = 128 (x) + 64 (h); same two-group fusion.
// ---------------------------------------------------------------------------
__global__ __launch_bounds__(512) void lstm_l1(
    const _Float16* __restrict__ out0,
    const float* __restrict__ WihF, const float* __restrict__ WhhF, const float* __restrict__ bF,
    const float* __restrict__ WihB, const float* __restrict__ WhhB, const float* __restrict__ bB,
    float* __restrict__ pooled)
{
    const int tid  = threadIdx.x;
    const int grp  = tid >> 8;
    const int tid8 = tid & 255;
    const int w = tid8 >> 6, l = tid8 & 63, m = l & 15, q = l >> 4;

    const int gg  = blockIdx.x * 2 + grp;
    const int dir = gg & 1;
    const int b0  = (gg >> 1) * 16;

    const float* Wih = dir ? WihB : WihF;
    const float* Whh = dir ? WhhB : WhhF;
    const float* bia = dir ? bB   : bF;

    half8 Bf[4][6];   // [g][0..1]=Whh, [g][2..5]=Wih
    float bv[4];
#pragma unroll
    for (int g = 0; g < 4; ++g) {
        const int n = g * 64 + w * 16 + m;
        bv[g] = bia[n];
#pragma unroll
        for (int s = 0; s < 6; ++s) {
            const float* src = (s < 2) ? (Whh + n * 64 + s * 32 + q * 8)
                                       : (Wih + n * 128 + (s - 2) * 32 + q * 8);
            half8 tmp;
#pragma unroll
            for (int j = 0; j < 8; ++j) tmp[j] = (_Float16)src[j];
            Bf[g][s] = tmp;
        }
    }

    __shared__ _Float16 hbuf[2][2][1024];
    ((unsigned long long*)hbuf[grp][0])[tid8] = 0ULL;
    __syncthreads();

    float c[4]  = {0.f, 0.f, 0.f, 0.f};
    float hs[4] = {0.f, 0.f, 0.f, 0.f};
    const int dt = dir ? -1 : 1;
    int t = dir ? TT - 1 : 0;
    const _Float16* xrow = out0 + (size_t)(b0 + m) * TT * 128 + q * 8;
    const int swz = (m & 7) * 16;

    half8 ax[4], axn[4];
#pragma unroll
    for (int s4 = 0; s4 < 4; ++s4) ax[s4] = *(const half8*)(xrow + t * 128 + s4 * 32);
    int t1 = t + dt; if (t1 < 0 || t1 >= TT) t1 = t;
#pragma unroll
    for (int s4 = 0; s4 < 4; ++s4) axn[s4] = *(const half8*)(xrow + t1 * 128 + s4 * 32);
    int p = 0;

    for (int s = 0; s < TT; ++s) {
        int t2 = t + 2 * dt; if (t2 < 0 || t2 >= TT) t2 = t;
        half8 axn2[4];
#pragma unroll
        for (int s4 = 0; s4 < 4; ++s4) axn2[s4] = *(const half8*)(xrow + t2 * 128 + s4 * 32);

        const char* hb = (const char*)hbuf[grp][p];
        half8 ah0 = *(const half8*)(hb + m * 128 + ((     q * 16 + swz) & 127));
        half8 ah1 = *(const half8*)(hb + m * 128 + ((64 + q * 16 + swz) & 127));

        f32x4 acc[4];
#pragma unroll
        for (int g = 0; g < 4; ++g) {
            f32x4 a = {bv[g], bv[g], bv[g], bv[g]};
            a = __builtin_amdgcn_mfma_f32_16x16x32_f16(ax[0], Bf[g][2], a, 0, 0, 0);
            a = __builtin_amdgcn_mfma_f32_16x16x32_f16(ax[1], Bf[g][3], a, 0, 0, 0);
            a = __builtin_amdgcn_mfma_f32_16x16x32_f16(ax[2], Bf[g][4], a, 0, 0, 0);
            a = __builtin_amdgcn_mfma_f32_16x16x32_f16(ax[3], Bf[g][5], a, 0, 0, 0);
            a = __builtin_amdgcn_mfma_f32_16x16x32_f16(ah0,   Bf[g][0], a, 0, 0, 0);
            acc[g] = __builtin_amdgcn_mfma_f32_16x16x32_f16(ah1, Bf[g][1], a, 0, 0, 0);
        }

        char* hbn = (char*)hbuf[grp][p ^ 1];
#pragma unroll
        for (int i = 0; i < 4; ++i) {
            float e_i = sigm(acc[0][i]), e_f = sigm(acc[1][i]);
            float e_g = tanh_fast(acc[2][i]), e_o = sigm(acc[3][i]);
            c[i] = e_f * c[i] + e_i * e_g;
            float hh = e_o * tanh_fast(c[i]);
            hs[i] += hh;
            const int ch = q * 4 + i;
            *(_Float16*)(hbn + ch * 128 + (((w * 16 + m) * 2 + (ch & 7) * 16) & 127)) = (_Float16)hh;
        }
        __syncthreads();
        p ^= 1; t += dt;
#pragma unroll
        for (int s4 = 0; s4 < 4; ++s4) { ax[s4] = axn[s4]; axn[s4] = axn2[s4]; }
    }

#pragma unroll
    for (int i = 0; i < 4; ++i)
        pooled[(size_t)(b0 + q * 4 + i) * 128 + dir * 64 + w * 16 + m] = hs[i];
}

// ---------------------------------------------------------------------------
// Head: out[b] = dot(pooled[b], fcw) / T + fcb
// ---------------------------------------------------------------------------
__global__ __launch_bounds__(64) void fc_head(
    const float* __restrict__ pooled,
    const float* __restrict__ fcw, const float* __restrict__ fcb,
    float* __restrict__ out)
{
    const int b = blockIdx.x;
    const int l = threadIdx.x;
    float v = pooled[b * 128 + l] * fcw[l] + pooled[b * 128 + 64 + l] * fcw[64 + l];
#pragma unroll
    for (int o = 32; o > 0; o >>= 1) v += __shfl_down(v, o);
    if (l == 0) out[b] = v * (1.f / (float)TT) + fcb[0];
}

extern "C" void kernel_launch(void* const* d_in, const int* in_sizes, int n_in,
                              void* d_out, int out_size, void* d_ws, size_t ws_size,
                              hipStream_t stream) {
    const float* x       = (const float*)d_in[0];
    const float* Wih_l0f = (const float*)d_in[1];
    const float* Whh_l0f = (const float*)d_in[2];
    const float* b_l0f   = (const float*)d_in[3];
    const float* Wih_l0b = (const float*)d_in[4];
    const float* Whh_l0b = (const float*)d_in[5];
    const float* b_l0b   = (const float*)d_in[6];
    const float* Wih_l1f = (const float*)d_in[7];
    const float* Whh_l1f = (const float*)d_in[8];
    const float* b_l1f   = (const float*)d_in[9];
    const float* Wih_l1b = (const float*)d_in[10];
    const float* Whh_l1b = (const float*)d_in[11];
    const float* b_l1b   = (const float*)d_in[12];
    const float* fcw     = (const float*)d_in[13];
    const float* fcb     = (const float*)d_in[14];

    const size_t o_xpad   = 0;
    const size_t o_out0   = o_xpad + (size_t)BB * TT * 32 * 2;
    const size_t o_pooled = o_out0 + (size_t)BB * TT * 128 * 2;

    _Float16* xpad   = (_Float16*)((char*)d_ws + o_xpad);
    _Float16* out0   = (_Float16*)((char*)d_ws + o_out0);
    float*    pooled = (float*)((char*)d_ws + o_pooled);

    xpad_prep<<<(BB * TT * 4) / 256, 256, 0, stream>>>(x, xpad);
    lstm_l0<<<32, 512, 0, stream>>>(xpad, Wih_l0f, Whh_l0f, b_l0f,
                                    Wih_l0b, Whh_l0b, b_l0b, out0);
    lstm_l1<<<32, 512, 0, stream>>>(out0, Wih_l1f, Whh_l1f, b_l1f,
                                    Wih_l1b, Whh_l1b, b_l1b, pooled);
    fc_head<<<BB, 64, 0, stream>>>(pooled, fcw, fcb, (float*)d_out);
}

// Round 8
// 951.320 us; speedup vs baseline: 1.2667x; 1.2667x over previous
//
#include <hip/hip_runtime.h>

#define H  64
#define TT 512
#define BB 512

typedef _Float16 half8 __attribute__((ext_vector_type(8)));
typedef float    f32x4 __attribute__((ext_vector_type(4)));

// ---------------------------------------------------------------------------
// Activations via clamped 7/6 Pade tanh: 1 trans op (rcp) per activation
// instead of 2 (exp+rcp). Trans pipe is the per-CU step bottleneck.
// tanh(x) ~ x(135135+17325v+378v^2+v^3)/(135135+62370v+3150v^2+28v^3), v=x^2
// |Pade err| < 2e-5 on [-4,4]; clamp err <= 6.7e-4 beyond.
// ---------------------------------------------------------------------------
__device__ __forceinline__ float pade_tanh(float x) {   // requires |x| <= 4
    float v = x * x;
    float n = x * __builtin_fmaf(v, __builtin_fmaf(v, (v + 378.f), 17325.f), 135135.f);
    float d = __builtin_fmaf(v, __builtin_fmaf(v, __builtin_fmaf(v, 28.f, 3150.f), 62370.f), 135135.f);
    return n * __builtin_amdgcn_rcpf(d);
}
__device__ __forceinline__ float tanh_fast(float x) {
    float xc = __builtin_fminf(__builtin_fmaxf(x, -4.f), 4.f);
    return pade_tanh(xc);
}
__device__ __forceinline__ float sigm(float x) {        // 0.5 + 0.5*tanh(x/2)
    float y = 0.5f * x;
    y = __builtin_fminf(__builtin_fmaxf(y, -4.f), 4.f);
    return __builtin_fmaf(0.5f, pade_tanh(y), 0.5f);
}

// ---------------------------------------------------------------------------
// xpad: [B*T][32] fp16, cols 0..3 = x (fp32->fp16), cols 4..31 = 0.
// ---------------------------------------------------------------------------
__global__ __launch_bounds__(256) void xpad_prep(const float* __restrict__ x,
                                                 _Float16* __restrict__ xpad) {
    int gid = blockIdx.x * 256 + threadIdx.x;
    int row = gid >> 2, q = gid & 3;
    half8 v = {0,0,0,0,0,0,0,0};
    if (q == 0) {
        float4 xv = ((const float4*)x)[row];
        v[0] = (_Float16)xv.x; v[1] = (_Float16)xv.y;
        v[2] = (_Float16)xv.z; v[3] = (_Float16)xv.w;
    }
    *(half8*)(xpad + (size_t)row * 32 + q * 8) = v;
}

// ---------------------------------------------------------------------------
// MFMA LSTM layer 0. Block = 256 thr = 4 waves, 16 chains (same dir).
// A = [h fp16 (LDS, swizzled) | xpad_t (global, prefetched)], K = 96.
// B (Whh|Wih0 fp16) lives in VGPRs. State c fp32 in regs. 1 barrier/step.
// (R4 structure — fastest measured; only activations changed this round.)
// ---------------------------------------------------------------------------
__global__ __launch_bounds__(256) void lstm_l0(
    const _Float16* __restrict__ xpad,
    const float* __restrict__ WihF, const float* __restrict__ WhhF, const float* __restrict__ bF,
    const float* __restrict__ WihB, const float* __restrict__ WhhB, const float* __restrict__ bB,
    _Float16* __restrict__ out0)
{
    const int dir = blockIdx.x & 1;
    const int b0  = (blockIdx.x >> 1) * 16;
    const int tid = threadIdx.x;
    const int w = tid >> 6, l = tid & 63, m = l & 15, q = l >> 4;

    const float* Wih = dir ? WihB : WihF;
    const float* Whh = dir ? WhhB : WhhF;
    const float* bia = dir ? bB   : bF;

    half8 Bh[4][2], Bx[4];
    float bv[4];
#pragma unroll
    for (int g = 0; g < 4; ++g) {
        const int n = g * 64 + w * 16 + m;
        bv[g] = bia[n];
#pragma unroll
        for (int s = 0; s < 2; ++s) {
            const float* src = Whh + n * 64 + s * 32 + q * 8;
            half8 tmp;
#pragma unroll
            for (int j = 0; j < 8; ++j) tmp[j] = (_Float16)src[j];
            Bh[g][s] = tmp;
        }
        half8 tx;
#pragma unroll
        for (int j = 0; j < 8; ++j) {
            int k = q * 8 + j;
            tx[j] = (k < 4) ? (_Float16)Wih[n * 4 + k] : (_Float16)0.f;
        }
        Bx[g] = tx;
    }

    __shared__ _Float16 hbuf[2][1024];
    ((unsigned long long*)hbuf)[tid] = 0ULL;
    __syncthreads();

    float c[4] = {0.f, 0.f, 0.f, 0.f};
    const int dt = dir ? -1 : 1;
    int t = dir ? TT - 1 : 0;
    const _Float16* xrow = xpad + (size_t)(b0 + m) * TT * 32 + q * 8;
    half8 ax = *(const half8*)(xrow + t * 32);
    int p = 0;
    const int swz = (m & 7) * 16;

    for (int s = 0; s < TT; ++s) {
        int tn = t + ((s + 1 < TT) ? dt : 0);
        half8 axn = *(const half8*)(xrow + tn * 32);

        const char* hb = (const char*)hbuf[p];
        half8 ah0 = *(const half8*)(hb + m * 128 + ((     q * 16 + swz) & 127));
        half8 ah1 = *(const half8*)(hb + m * 128 + ((64 + q * 16 + swz) & 127));

        f32x4 acc[4];
#pragma unroll
        for (int g = 0; g < 4; ++g) {
            f32x4 a = {bv[g], bv[g], bv[g], bv[g]};
            a = __builtin_amdgcn_mfma_f32_16x16x32_f16(ax,  Bx[g],    a, 0, 0, 0);
            a = __builtin_amdgcn_mfma_f32_16x16x32_f16(ah0, Bh[g][0], a, 0, 0, 0);
            acc[g] = __builtin_amdgcn_mfma_f32_16x16x32_f16(ah1, Bh[g][1], a, 0, 0, 0);
        }

        char* hbn = (char*)hbuf[p ^ 1];
#pragma unroll
        for (int i = 0; i < 4; ++i) {
            float e_i = sigm(acc[0][i]), e_f = sigm(acc[1][i]);
            float e_g = tanh_fast(acc[2][i]), e_o = sigm(acc[3][i]);
            c[i] = e_f * c[i] + e_i * e_g;
            float hh = e_o * tanh_fast(c[i]);
            const int ch = q * 4 + i;
            out0[((size_t)(b0 + ch) * TT + t) * 128 + dir * 64 + w * 16 + m] = (_Float16)hh;
            *(_Float16*)(hbn + ch * 128 + (((w * 16 + m) * 2 + (ch & 7) * 16) & 127)) = (_Float16)hh;
        }
        __syncthreads();
        p ^= 1; t += dt; ax = axn;
    }
}

// ---------------------------------------------------------------------------
// MFMA LSTM layer 1: K = 128 (x from out0) + 64 (h). Accumulates hsum.
// ---------------------------------------------------------------------------
__global__ __launch_bounds__(256) void lstm_l1(
    const _Float16* __restrict__ out0,
    const float* __restrict__ WihF, const float* __restrict__ WhhF, const float* __restrict__ bF,
    const float* __restrict__ WihB, const float* __restrict__ WhhB, const float* __restrict__ bB,
    float* __restrict__ pooled)
{
    const int dir = blockIdx.x & 1;
    const int b0  = (blockIdx.x >> 1) * 16;
    const int tid = threadIdx.x;
    const int w = tid >> 6, l = tid & 63, m = l & 15, q = l >> 4;

    const float* Wih = dir ? WihB : WihF;
    const float* Whh = dir ? WhhB : WhhF;
    const float* bia = dir ? bB   : bF;

    half8 Bf[4][6];   // [g][0..1]=Whh, [g][2..5]=Wih
    float bv[4];
#pragma unroll
    for (int g = 0; g < 4; ++g) {
        const int n = g * 64 + w * 16 + m;
        bv[g] = bia[n];
#pragma unroll
        for (int s = 0; s < 6; ++s) {
            const float* src = (s < 2) ? (Whh + n * 64 + s * 32 + q * 8)
                                       : (Wih + n * 128 + (s - 2) * 32 + q * 8);
            half8 tmp;
#pragma unroll
            for (int j = 0; j < 8; ++j) tmp[j] = (_Float16)src[j];
            Bf[g][s] = tmp;
        }
    }

    __shared__ _Float16 hbuf[2][1024];
    ((unsigned long long*)hbuf)[tid] = 0ULL;
    __syncthreads();

    float c[4]  = {0.f, 0.f, 0.f, 0.f};
    float hs[4] = {0.f, 0.f, 0.f, 0.f};
    const int dt = dir ? -1 : 1;
    int t = dir ? TT - 1 : 0;
    const _Float16* xrow = out0 + (size_t)(b0 + m) * TT * 128 + q * 8;
    const int swz = (m & 7) * 16;

    half8 ax[4];
#pragma unroll
    for (int s4 = 0; s4 < 4; ++s4) ax[s4] = *(const half8*)(xrow + t * 128 + s4 * 32);
    int p = 0;

    for (int s = 0; s < TT; ++s) {
        int tn = t + ((s + 1 < TT) ? dt : 0);
        half8 axn[4];
#pragma unroll
        for (int s4 = 0; s4 < 4; ++s4) axn[s4] = *(const half8*)(xrow + tn * 128 + s4 * 32);

        const char* hb = (const char*)hbuf[p];
        half8 ah0 = *(const half8*)(hb + m * 128 + ((     q * 16 + swz) & 127));
        half8 ah1 = *(const half8*)(hb + m * 128 + ((64 + q * 16 + swz) & 127));

        f32x4 acc[4];
#pragma unroll
        for (int g = 0; g < 4; ++g) {
            f32x4 a = {bv[g], bv[g], bv[g], bv[g]};
            a = __builtin_amdgcn_mfma_f32_16x16x32_f16(ax[0], Bf[g][2], a, 0, 0, 0);
            a = __builtin_amdgcn_mfma_f32_16x16x32_f16(ax[1], Bf[g][3], a, 0, 0, 0);
            a = __builtin_amdgcn_mfma_f32_16x16x32_f16(ax[2], Bf[g][4], a, 0, 0, 0);
            a = __builtin_amdgcn_mfma_f32_16x16x32_f16(ax[3], Bf[g][5], a, 0, 0, 0);
            a = __builtin_amdgcn_mfma_f32_16x16x32_f16(ah0,   Bf[g][0], a, 0, 0, 0);
            acc[g] = __builtin_amdgcn_mfma_f32_16x16x32_f16(ah1, Bf[g][1], a, 0, 0, 0);
        }

        char* hbn = (char*)hbuf[p ^ 1];
#pragma unroll
        for (int i = 0; i < 4; ++i) {
            float e_i = sigm(acc[0][i]), e_f = sigm(acc[1][i]);
            float e_g = tanh_fast(acc[2][i]), e_o = sigm(acc[3][i]);
            c[i] = e_f * c[i] + e_i * e_g;
            float hh = e_o * tanh_fast(c[i]);
            hs[i] += hh;
            const int ch = q * 4 + i;
            *(_Float16*)(hbn + ch * 128 + (((w * 16 + m) * 2 + (ch & 7) * 16) & 127)) = (_Float16)hh;
        }
        __syncthreads();
        p ^= 1; t += dt;
#pragma unroll
        for (int s4 = 0; s4 < 4; ++s4) ax[s4] = axn[s4];
    }

#pragma unroll
    for (int i = 0; i < 4; ++i)
        pooled[(size_t)(b0 + q * 4 + i) * 128 + dir * 64 + w * 16 + m] = hs[i];
}

// ---------------------------------------------------------------------------
// Head: out[b] = dot(pooled[b], fcw) / T + fcb
// ---------------------------------------------------------------------------
__global__ __launch_bounds__(64) void fc_head(
    const float* __restrict__ pooled,
    const float* __restrict__ fcw, const float* __restrict__ fcb,
    float* __restrict__ out)
{
    const int b = blockIdx.x;
    const int l = threadIdx.x;
    float v = pooled[b * 128 + l] * fcw[l] + pooled[b * 128 + 64 + l] * fcw[64 + l];
#pragma unroll
    for (int o = 32; o > 0; o >>= 1) v += __shfl_down(v, o);
    if (l == 0) out[b] = v * (1.f / (float)TT) + fcb[0];
}

extern "C" void kernel_launch(void* const* d_in, const int* in_sizes, int n_in,
                              void* d_out, int out_size, void* d_ws, size_t ws_size,
                              hipStream_t stream) {
    const float* x       = (const float*)d_in[0];
    const float* Wih_l0f = (const float*)d_in[1];
    const float* Whh_l0f = (const float*)d_in[2];
    const float* b_l0f   = (const float*)d_in[3];
    const float* Wih_l0b = (const float*)d_in[4];
    const float* Whh_l0b = (const float*)d_in[5];
    const float* b_l0b   = (const float*)d_in[6];
    const float* Wih_l1f = (const float*)d_in[7];
    const float* Whh_l1f = (const float*)d_in[8];
    const float* b_l1f   = (const float*)d_in[9];
    const float* Wih_l1b = (const float*)d_in[10];
    const float* Whh_l1b = (const float*)d_in[11];
    const float* b_l1b   = (const float*)d_in[12];
    const float* fcw     = (const float*)d_in[13];
    const float* fcb     = (const float*)d_in[14];

    const size_t o_xpad   = 0;
    const size_t o_out0   = o_xpad + (size_t)BB * TT * 32 * 2;
    const size_t o_pooled = o_out0 + (size_t)BB * TT * 128 * 2;

    _Float16* xpad   = (_Float16*)((char*)d_ws + o_xpad);
    _Float16* out0   = (_Float16*)((char*)d_ws + o_out0);
    float*    pooled = (float*)((char*)d_ws + o_pooled);

    xpad_prep<<<(BB * TT * 4) / 256, 256, 0, stream>>>(x, xpad);
    lstm_l0<<<(BB / 16) * 2, 256, 0, stream>>>(xpad, Wih_l0f, Whh_l0f, b_l0f,
                                               Wih_l0b, Whh_l0b, b_l0b, out0);
    lstm_l1<<<(BB / 16) * 2, 256, 0, stream>>>(out0, Wih_l1f, Whh_l1f, b_l1f,
                                               Wih_l1b, Whh_l1b, b_l1b, pooled);
    fc_head<<<BB, 64, 0, stream>>>(pooled, fcw, fcb, (float*)d_out);
}

// Round 9
// 680.925 us; speedup vs baseline: 1.7697x; 1.3971x over previous
//
#include <hip/hip_runtime.h>

#define H  64
#define TT 512
#define BB 512

typedef _Float16 half8 __attribute__((ext_vector_type(8)));
typedef float    f32x4 __attribute__((ext_vector_type(4)));

__device__ __forceinline__ float frcp(float x) { return __builtin_amdgcn_rcpf(x); }
__device__ __forceinline__ float sigm(float x) { return frcp(1.f + __expf(-x)); }
__device__ __forceinline__ float tanh_fast(float x) { return 1.f - 2.f * frcp(__expf(2.f * x) + 1.f); }

// ---------------------------------------------------------------------------
// xpad: [B*T][32] fp16, cols 0..3 = x (fp32->fp16), cols 4..31 = 0.
// ---------------------------------------------------------------------------
__global__ __launch_bounds__(256) void xpad_prep(const float* __restrict__ x,
                                                 _Float16* __restrict__ xpad) {
    int gid = blockIdx.x * 256 + threadIdx.x;
    int row = gid >> 2, q = gid & 3;
    half8 v = {0,0,0,0,0,0,0,0};
    if (q == 0) {
        float4 xv = ((const float4*)x)[row];
        v[0] = (_Float16)xv.x; v[1] = (_Float16)xv.y;
        v[2] = (_Float16)xv.z; v[3] = (_Float16)xv.w;
    }
    *(half8*)(xpad + (size_t)row * 32 + q * 8) = v;
}

// ---------------------------------------------------------------------------
// Layer 0: 4 chains/block, 256 blocks (all CUs). A = WEIGHTS (M=16 rows =
// 4 unit-slots x 4 gates), B = DATA (N=16 cols = 4 chains x 4 replicas;
// lane n holds chain n&3). After subblock ub=m>>2's MFMAs, lane (m,q) holds
// all 4 gates of cell (chain m&3, unit w*16+(m>>2)*4+q): 1 cell/lane.
// K = 64 (h from LDS) + 32 (xpad, prefetched) = 3 slices; 12 MFMA/wave/step.
// ---------------------------------------------------------------------------
__global__ __launch_bounds__(256) void lstm_l0(
    const _Float16* __restrict__ xpad,
    const float* __restrict__ WihF, const float* __restrict__ WhhF, const float* __restrict__ bF,
    const float* __restrict__ WihB, const float* __restrict__ WhhB, const float* __restrict__ bB,
    _Float16* __restrict__ out0)
{
    const int dir = blockIdx.x & 1;
    const int b0  = (blockIdx.x >> 1) * 4;          // 4 chains per block
    const int tid = threadIdx.x;
    const int w = tid >> 6, l = tid & 63, m = l & 15, q = l >> 4;
    const int ch = m & 3;                            // this lane's chain
    const int ubo = m >> 2;                          // owned subblock
    const int uo  = w * 16 + ubo * 4 + q;            // owned unit

    const float* Wih = dir ? WihB : WihF;
    const float* Whh = dir ? WhhB : WhhF;
    const float* bia = dir ? bB   : bF;

    // A-frags (weights): Af[ub][s], s=0,1 -> Whh k-windows, s=2 -> Wih (padded K=32)
    half8 Af[4][3];
    f32x4 bv[4];
#pragma unroll
    for (int ub = 0; ub < 4; ++ub) {
        const int wrow = (m & 3) * 64 + (w * 16 + ub * 4 + (m >> 2)); // gate*64+unit
#pragma unroll
        for (int s = 0; s < 3; ++s) {
            half8 tmp;
            if (s < 2) {
                const float* src = Whh + wrow * 64 + s * 32 + q * 8;
#pragma unroll
                for (int j = 0; j < 8; ++j) tmp[j] = (_Float16)src[j];
            } else {
#pragma unroll
                for (int j = 0; j < 8; ++j) {
                    int k = q * 8 + j;
                    tmp[j] = (k < 4) ? (_Float16)Wih[wrow * 4 + k] : (_Float16)0.f;
                }
            }
            Af[ub][s] = tmp;
        }
        const int u = w * 16 + ub * 4 + q;
        bv[ub] = (f32x4){bia[u], bia[64 + u], bia[128 + u], bia[192 + u]};
    }

    __shared__ _Float16 hbuf[2][4][64];              // [pingpong][chain][unit]
    ((unsigned int*)hbuf)[tid] = 0u;                 // zero both buffers (1 KB)
    __syncthreads();

    float c = 0.f;
    const int dt = dir ? -1 : 1;
    int t = dir ? TT - 1 : 0;
    const _Float16* xrow = xpad + (size_t)(b0 + ch) * TT * 32 + q * 8;
    half8 ax = *(const half8*)(xrow + t * 32);
    int p = 0;

    for (int s = 0; s < TT; ++s) {
        int tn = t + ((s + 1 < TT) ? dt : 0);
        half8 axn = *(const half8*)(xrow + tn * 32);

        half8 ah0 = *(const half8*)&hbuf[p][ch][q * 8];
        half8 ah1 = *(const half8*)&hbuf[p][ch][32 + q * 8];

        f32x4 g_own;
#pragma unroll
        for (int ub = 0; ub < 4; ++ub) {
            f32x4 a = bv[ub];
            a = __builtin_amdgcn_mfma_f32_16x16x32_f16(Af[ub][2], ax,  a, 0, 0, 0);
            a = __builtin_amdgcn_mfma_f32_16x16x32_f16(Af[ub][0], ah0, a, 0, 0, 0);
            a = __builtin_amdgcn_mfma_f32_16x16x32_f16(Af[ub][1], ah1, a, 0, 0, 0);
            if (ub == ubo) g_own = a;
        }

        float e_i = sigm(g_own[0]), e_f = sigm(g_own[1]);
        float e_g = tanh_fast(g_own[2]), e_o = sigm(g_own[3]);
        c = e_f * c + e_i * e_g;
        float hh = e_o * tanh_fast(c);

        out0[((size_t)(b0 + ch) * TT + t) * 128 + dir * 64 + uo] = (_Float16)hh;
        hbuf[p ^ 1][ch][uo] = (_Float16)hh;
        __syncthreads();
        p ^= 1; t += dt; ax = axn;
    }
}

// ---------------------------------------------------------------------------
// Layer 1: same scheme, K = 64 (h) + 128 (x from out0) = 6 slices; 24 MFMA.
// ---------------------------------------------------------------------------
__global__ __launch_bounds__(256) void lstm_l1(
    const _Float16* __restrict__ out0,
    const float* __restrict__ WihF, const float* __restrict__ WhhF, const float* __restrict__ bF,
    const float* __restrict__ WihB, const float* __restrict__ WhhB, const float* __restrict__ bB,
    float* __restrict__ pooled)
{
    const int dir = blockIdx.x & 1;
    const int b0  = (blockIdx.x >> 1) * 4;
    const int tid = threadIdx.x;
    const int w = tid >> 6, l = tid & 63, m = l & 15, q = l >> 4;
    const int ch = m & 3;
    const int ubo = m >> 2;
    const int uo  = w * 16 + ubo * 4 + q;

    const float* Wih = dir ? WihB : WihF;
    const float* Whh = dir ? WhhB : WhhF;
    const float* bia = dir ? bB   : bF;

    // A-frags: s=0,1 -> Whh, s=2..5 -> Wih
    half8 Af[4][6];
    f32x4 bv[4];
#pragma unroll
    for (int ub = 0; ub < 4; ++ub) {
        const int wrow = (m & 3) * 64 + (w * 16 + ub * 4 + (m >> 2));
#pragma unroll
        for (int s = 0; s < 6; ++s) {
            const float* src = (s < 2) ? (Whh + wrow * 64 + s * 32 + q * 8)
                                       : (Wih + wrow * 128 + (s - 2) * 32 + q * 8);
            half8 tmp;
#pragma unroll
            for (int j = 0; j < 8; ++j) tmp[j] = (_Float16)src[j];
            Af[ub][s] = tmp;
        }
        const int u = w * 16 + ub * 4 + q;
        bv[ub] = (f32x4){bia[u], bia[64 + u], bia[128 + u], bia[192 + u]};
    }

    __shared__ _Float16 hbuf[2][4][64];
    ((unsigned int*)hbuf)[tid] = 0u;
    __syncthreads();

    float c = 0.f, hs = 0.f;
    const int dt = dir ? -1 : 1;
    int t = dir ? TT - 1 : 0;
    const _Float16* xrow = out0 + (size_t)(b0 + ch) * TT * 128 + q * 8;

    half8 ax[4];
#pragma unroll
    for (int s4 = 0; s4 < 4; ++s4) ax[s4] = *(const half8*)(xrow + t * 128 + s4 * 32);
    int p = 0;

    for (int s = 0; s < TT; ++s) {
        int tn = t + ((s + 1 < TT) ? dt : 0);
        half8 axn[4];
#pragma unroll
        for (int s4 = 0; s4 < 4; ++s4) axn[s4] = *(const half8*)(xrow + tn * 128 + s4 * 32);

        half8 ah0 = *(const half8*)&hbuf[p][ch][q * 8];
        half8 ah1 = *(const half8*)&hbuf[p][ch][32 + q * 8];

        f32x4 g_own;
#pragma unroll
        for (int ub = 0; ub < 4; ++ub) {
            f32x4 a = bv[ub];
            a = __builtin_amdgcn_mfma_f32_16x16x32_f16(Af[ub][2], ax[0], a, 0, 0, 0);
            a = __builtin_amdgcn_mfma_f32_16x16x32_f16(Af[ub][3], ax[1], a, 0, 0, 0);
            a = __builtin_amdgcn_mfma_f32_16x16x32_f16(Af[ub][4], ax[2], a, 0, 0, 0);
            a = __builtin_amdgcn_mfma_f32_16x16x32_f16(Af[ub][5], ax[3], a, 0, 0, 0);
            a = __builtin_amdgcn_mfma_f32_16x16x32_f16(Af[ub][0], ah0,   a, 0, 0, 0);
            a = __builtin_amdgcn_mfma_f32_16x16x32_f16(Af[ub][1], ah1,   a, 0, 0, 0);
            if (ub == ubo) g_own = a;
        }

        float e_i = sigm(g_own[0]), e_f = sigm(g_own[1]);
        float e_g = tanh_fast(g_own[2]), e_o = sigm(g_own[3]);
        c = e_f * c + e_i * e_g;
        float hh = e_o * tanh_fast(c);
        hs += hh;

        hbuf[p ^ 1][ch][uo] = (_Float16)hh;
        __syncthreads();
        p ^= 1; t += dt;
#pragma unroll
        for (int s4 = 0; s4 < 4; ++s4) ax[s4] = axn[s4];
    }

    pooled[(size_t)(b0 + ch) * 128 + dir * 64 + uo] = hs;
}

// ---------------------------------------------------------------------------
// Head: out[b] = dot(pooled[b], fcw) / T + fcb
// ---------------------------------------------------------------------------
__global__ __launch_bounds__(64) void fc_head(
    const float* __restrict__ pooled,
    const float* __restrict__ fcw, const float* __restrict__ fcb,
    float* __restrict__ out)
{
    const int b = blockIdx.x;
    const int l = threadIdx.x;
    float v = pooled[b * 128 + l] * fcw[l] + pooled[b * 128 + 64 + l] * fcw[64 + l];
#pragma unroll
    for (int o = 32; o > 0; o >>= 1) v += __shfl_down(v, o);
    if (l == 0) out[b] = v * (1.f / (float)TT) + fcb[0];
}

extern "C" void kernel_launch(void* const* d_in, const int* in_sizes, int n_in,
                              void* d_out, int out_size, void* d_ws, size_t ws_size,
                              hipStream_t stream) {
    const float* x       = (const float*)d_in[0];
    const float* Wih_l0f = (const float*)d_in[1];
    const float* Whh_l0f = (const float*)d_in[2];
    const float* b_l0f   = (const float*)d_in[3];
    const float* Wih_l0b = (const float*)d_in[4];
    const float* Whh_l0b = (const float*)d_in[5];
    const float* b_l0b   = (const float*)d_in[6];
    const float* Wih_l1f = (const float*)d_in[7];
    const float* Whh_l1f = (const float*)d_in[8];
    const float* b_l1f   = (const float*)d_in[9];
    const float* Wih_l1b = (const float*)d_in[10];
    const float* Whh_l1b = (const float*)d_in[11];
    const float* b_l1b   = (const float*)d_in[12];
    const float* fcw     = (const float*)d_in[13];
    const float* fcb     = (const float*)d_in[14];

    const size_t o_xpad   = 0;
    const size_t o_out0   = o_xpad + (size_t)BB * TT * 32 * 2;
    const size_t o_pooled = o_out0 + (size_t)BB * TT * 128 * 2;

    _Float16* xpad   = (_Float16*)((char*)d_ws + o_xpad);
    _Float16* out0   = (_Float16*)((char*)d_ws + o_out0);
    float*    pooled = (float*)((char*)d_ws + o_pooled);

    xpad_prep<<<(BB * TT * 4) / 256, 256, 0, stream>>>(x, xpad);
    lstm_l0<<<(BB / 4) * 2, 256, 0, stream>>>(xpad, Wih_l0f, Whh_l0f, b_l0f,
                                              Wih_l0b, Whh_l0b, b_l0b, out0);
    lstm_l1<<<(BB / 4) * 2, 256, 0, stream>>>(out0, Wih_l1f, Whh_l1f, b_l1f,
                                              Wih_l1b, Whh_l1b, b_l1b, pooled);
    fc_head<<<BB, 64, 0, stream>>>(pooled, fcw, fcb, (float*)d_out);
}